// Round 4
// baseline (1199.273 us; speedup 1.0000x reference)
//
#include <hip/hip_runtime.h>
#include <stdint.h>

#define NQ 14
#define NSTATE 16384        // 2^14
#define NPASS 5
#define NGEN 8
#define THREADS 512

// ---------------- compile-time GF(2) circuit algebra ----------------
struct Mat { uint16_t col[NQ]; };
struct Tables {
    uint16_t mask[NPASS][NQ];  // pairing mask m = L^{-1} e_w
    uint16_t rho [NPASS][NQ];  // role parity row_w(L)
    uint16_t zrho[NQ];         // measurement parity rows (final L)
    bool ok;
};

// index map of the full CNOT ring: CNOT(i,(i+1)%14) applied i=0..13 in order
constexpr uint16_t ring_apply(uint16_t j) {
    for (int i = 0; i < NQ; ++i) {
        int t = (i + 1) % NQ;
        j = (uint16_t)(j ^ (((j >> i) & 1u) << t));
    }
    return j;
}
constexpr Mat identity() { Mat m{}; for (int i=0;i<NQ;++i) m.col[i]=(uint16_t)(1u<<i); return m; }
constexpr uint16_t mat_row(const Mat& L, int r) {
    uint16_t v=0; for (int b=0;b<NQ;++b) v=(uint16_t)(v | (((L.col[b]>>r)&1u)<<b)); return v;
}
constexpr uint16_t mat_apply(const Mat& L, uint16_t x) {
    uint16_t r=0; for (int b=0;b<NQ;++b) if ((x>>b)&1u) r=(uint16_t)(r ^ L.col[b]); return r;
}
constexpr Mat inverse(const Mat& L, bool& ok) {
    uint32_t lrow[NQ]={}, irow[NQ]={};
    for (int r=0;r<NQ;++r){ lrow[r]=mat_row(L,r); irow[r]=1u<<r; }
    for (int c=0;c<NQ;++c){
        int piv=-1;
        for (int r=c;r<NQ;++r) if ((lrow[r]>>c)&1u){ piv=r; break; }
        if (piv<0){ ok=false; return identity(); }
        uint32_t tl=lrow[c]; lrow[c]=lrow[piv]; lrow[piv]=tl;
        uint32_t ti=irow[c]; irow[c]=irow[piv]; irow[piv]=ti;
        for (int r=0;r<NQ;++r) if (r!=c && ((lrow[r]>>c)&1u)){ lrow[r]^=lrow[c]; irow[r]^=irow[c]; }
    }
    Mat inv{};
    for (int w=0;w<NQ;++w){ uint16_t cv=0; for (int r=0;r<NQ;++r) cv=(uint16_t)(cv | (((irow[r]>>w)&1u)<<r)); inv.col[w]=cv; }
    return inv;
}
constexpr Tables build() {
    Tables t{}; t.ok = true;
    Mat L = identity();
    for (int p=0;p<NPASS;++p) {
        if (p>0) { Mat Ln{}; for (int b=0;b<NQ;++b) Ln.col[b]=ring_apply(L.col[b]); L=Ln; }
        bool ok = true; Mat inv = inverse(L, ok); if (!ok) t.ok = false;
        for (int w=0;w<NQ;++w) {
            t.mask[p][w] = inv.col[w];
            t.rho [p][w] = mat_row(L,w);
            // strong invariant: L * (L^{-1} e_w) == e_w
            if (mat_apply(L, inv.col[w]) != (uint16_t)(1u<<w)) t.ok = false;
        }
    }
    for (int w=0;w<NQ;++w) t.zrho[w] = mat_row(L,w);   // measurement after pass 4, no extra ring
    return t;
}
constexpr Tables TBL = build();
static_assert(TBL.ok, "GF2 table build failed");
static_assert(TBL.mask[0][0]==1 && TBL.rho[0][0]==1, "pass0 w0");
static_assert(TBL.mask[0][13]==(1u<<13) && TBL.rho[0][13]==(1u<<13), "pass0 w13");
static_assert(TBL.mask[1][0]==3,      "pass1 w0 mask (hand-computed)");
static_assert(TBL.rho [1][0]==0x3FFE, "pass1 w0 rho  (hand-computed)");
static_assert(TBL.mask[1][12]==0x3000,"pass1 w12 mask (hand-computed)");

__constant__ Tables d_TBL = TBL;

// ---------------- kernel ----------------
// One workgroup per circuit (b,g). Statevector (16384 f32 = 64KB) in LDS.
// 2 workgroups/CU (128.6KB of 160KB LDS), 16 waves/CU.
__global__ __launch_bounds__(THREADS)
void qgen_kernel(const float* __restrict__ x, const float* __restrict__ W,
                 const float* __restrict__ bias, float* __restrict__ out)
{
    __shared__ __align__(16) float A[NSTATE];
    __shared__ float CS[2][2][NQ];   // [scale 1x/2x][cos/sin][wire]
    __shared__ float zacc[NQ];

    const int blk = blockIdx.x;
    const int bb  = blk >> 3;        // batch index (NGEN=8)
    const int g   = blk & 7;
    const int tid = threadIdx.x;
    float4* A4 = (float4*)A;

    // per-circuit angles: theta_p = sum_q x[b,q]*W[g,q,p] + bias[g,p]
    if (tid < NQ) {
        float acc = bias[g*NQ + tid];
        #pragma unroll
        for (int q=0;q<NQ;++q) acc += x[bb*NQ+q] * W[(g*NQ+q)*NQ + tid];
        float h = 0.5f*acc;
        CS[0][0][tid]=cosf(h);   CS[0][1][tid]=sinf(h);    // RY(theta)
        CS[1][0][tid]=cosf(acc); CS[1][1][tid]=sinf(acc);  // RY(2*theta)
        zacc[tid]=0.f;
    }
    __syncthreads();

    // ---- pass 0 as direct product-state fill: A[i] = prod_w (bit?s:c) ----
    {
        // block index bk: bits[8:0]=tid, bits[11:9]=it  -> wires 2..10 fixed per thread
        float tp = 1.f;
        #pragma unroll
        for (int wq=2; wq<11; ++wq)
            tp *= ((tid >> (wq-2)) & 1) ? CS[0][1][wq] : CS[0][0][wq];
        const float c0=CS[0][0][0], s0=CS[0][1][0], c1=CS[0][0][1], s1=CS[0][1][1];
        #pragma unroll
        for (int it=0; it<NSTATE/4/THREADS; ++it) {
            const int bk = it*THREADS + tid;
            float p2 = tp;
            #pragma unroll
            for (int wq=11; wq<NQ; ++wq)
                p2 *= ((bk >> (wq-2)) & 1) ? CS[0][1][wq] : CS[0][0][wq];
            A4[bk] = make_float4(p2*c0*c1, p2*s0*c1, p2*c0*s1, p2*s0*s1);
        }
    }
    __syncthreads();

    // ---- passes 1..4: 14 generalized RY gates each ----
    for (int p=1; p<NPASS; ++p) {
        const int sc = (p==NPASS-1) ? 0 : 1;   // last pass uses theta, middle use 2*theta
        for (int w=0; w<NQ; ++w) {
            const uint32_t m   = d_TBL.mask[p][w];
            const uint32_t rho = d_TBL.rho[p][w];
            const float c = CS[sc][0][w];
            const float s = CS[sc][1][w];
            const uint32_t mh = m >> 2, ml = m & 3u;

            if (mh == 0u) {
                // pairs live inside each float4
                #pragma unroll
                for (int it=0; it<NSTATE/4/THREADS; ++it) {
                    const int bk = it*THREADS + tid;
                    float4 v = A4[bk];
                    float vv[4] = {v.x, v.y, v.z, v.w};
                    float nv[4];
                    #pragma unroll
                    for (int j=0;j<4;++j) {
                        const int pj = __popc(rho & (uint32_t)(4*bk + j)) & 1;
                        nv[j] = fmaf(pj ? s : -s, vv[j^(int)ml], c*vv[j]);
                    }
                    A4[bk] = make_float4(nv[0],nv[1],nv[2],nv[3]);
                }
            } else if (mh < 64u) {
                // partner block is in another lane of the same wave: shuffle exchange
                #pragma unroll
                for (int it=0; it<NSTATE/4/THREADS; ++it) {
                    const int bk = it*THREADS + tid;
                    float4 v = A4[bk];
                    float ov[4];
                    ov[0]=__shfl_xor(v.x,(int)mh,64); ov[1]=__shfl_xor(v.y,(int)mh,64);
                    ov[2]=__shfl_xor(v.z,(int)mh,64); ov[3]=__shfl_xor(v.w,(int)mh,64);
                    float vv[4] = {v.x, v.y, v.z, v.w};
                    float nv[4];
                    #pragma unroll
                    for (int j=0;j<4;++j) {
                        const int pj = __popc(rho & (uint32_t)(4*bk + j)) & 1;
                        nv[j] = fmaf(pj ? s : -s, ov[j^(int)ml], c*vv[j]);
                    }
                    A4[bk] = make_float4(nv[0],nv[1],nv[2],nv[3]);
                }
            } else {
                // choose highest set bit (>=6) so each wave reads contiguous float4s
                const int tb = 31 - __clz(mh);
                #pragma unroll
                for (int it=0; it<NSTATE/8/THREADS; ++it) {
                    const int pk = it*THREADS + tid;            // 0..2047
                    const int b0 = ((pk >> tb) << (tb+1)) | (pk & ((1<<tb)-1));
                    const int b1 = b0 ^ (int)mh;
                    float4 v0 = A4[b0], v1 = A4[b1];
                    float a0[4]={v0.x,v0.y,v0.z,v0.w};
                    float a1[4]={v1.x,v1.y,v1.z,v1.w};
                    float n0[4], n1[4];
                    #pragma unroll
                    for (int j=0;j<4;++j) {
                        const int p0 = __popc(rho & (uint32_t)(4*b0 + j)) & 1;
                        const int p1 = __popc(rho & (uint32_t)(4*b1 + j)) & 1;
                        n0[j] = fmaf(p0 ? s : -s, a1[j^(int)ml], c*a0[j]);
                        n1[j] = fmaf(p1 ? s : -s, a0[j^(int)ml], c*a1[j]);
                    }
                    A4[b0] = make_float4(n0[0],n0[1],n0[2],n0[3]);
                    A4[b1] = make_float4(n1[0],n1[1],n1[2],n1[3]);
                }
            }
            __syncthreads();
        }
    }

    // ---- measurement: z_w = sum_i A[i]^2 * (1 - 2*parity(zrho_w & i)) ----
    float z[NQ];
    #pragma unroll
    for (int w=0;w<NQ;++w) z[w]=0.f;
    #pragma unroll
    for (int it=0; it<NSTATE/4/THREADS; ++it) {
        const int bk = it*THREADS + tid;
        float4 v = A4[bk];
        float pr[4] = {v.x*v.x, v.y*v.y, v.z*v.z, v.w*v.w};
        #pragma unroll
        for (int w=0;w<NQ;++w) {
            const uint32_t rho = d_TBL.zrho[w];
            float acc = 0.f;
            #pragma unroll
            for (int j=0;j<4;++j) {
                const int pj = __popc(rho & (uint32_t)(4*bk + j)) & 1;
                acc += pj ? -pr[j] : pr[j];
            }
            z[w] += acc;
        }
    }
    #pragma unroll
    for (int w=0;w<NQ;++w) {
        #pragma unroll
        for (int off=32; off; off>>=1) z[w] += __shfl_down(z[w], off, 64);
    }
    if ((tid & 63) == 0) {
        #pragma unroll
        for (int w=0;w<NQ;++w) atomicAdd(&zacc[w], z[w]);
    }
    __syncthreads();
    if (tid < NQ) out[blk*NQ + tid] = zacc[tid];
}

extern "C" void kernel_launch(void* const* d_in, const int* in_sizes, int n_in,
                              void* d_out, int out_size, void* d_ws, size_t ws_size,
                              hipStream_t stream) {
    (void)in_sizes; (void)n_in; (void)d_ws; (void)ws_size; (void)out_size;
    const float* x    = (const float*)d_in[0];   // [512,14]
    const float* W    = (const float*)d_in[1];   // [8,14,14]
    const float* bias = (const float*)d_in[2];   // [8,14]
    float* out = (float*)d_out;                  // [512, 8*14]
    qgen_kernel<<<dim3(512*NGEN), dim3(THREADS), 0, stream>>>(x, W, bias, out);
}

// Round 5
// 302.523 us; speedup vs baseline: 3.9642x; 3.9642x over previous
//
#include <hip/hip_runtime.h>
#include <stdint.h>

#define NQ 14
#define NPASS 5
#define NGEN 8
#define NTH 256
#define NBLK (512*NGEN)

// ---------------- constexpr helpers ----------------
constexpr int cpop16(uint32_t x){ int n=0; for(int i=0;i<16;++i) n+=(x>>i)&1; return n; }

// ---------------- GF(2) circuit algebra (round-0, verified on HW round 4) ----------------
struct Mat { uint16_t col[NQ]; };
struct Tables {
    uint16_t mask[NPASS][NQ];  // pairing mask m = L^{-1} e_w
    uint16_t rho [NPASS][NQ];  // role parity row_w(L)
    uint16_t zrho[NQ];         // measurement parity rows (final L)
    bool ok;
};
constexpr uint16_t ring_apply(uint16_t j) {
    for (int i = 0; i < NQ; ++i) { int t=(i+1)%NQ; j=(uint16_t)(j ^ (((j>>i)&1u)<<t)); }
    return j;
}
constexpr Mat identity() { Mat m{}; for (int i=0;i<NQ;++i) m.col[i]=(uint16_t)(1u<<i); return m; }
constexpr uint16_t mat_row(const Mat& L, int r) {
    uint16_t v=0; for (int b=0;b<NQ;++b) v=(uint16_t)(v | (((L.col[b]>>r)&1u)<<b)); return v;
}
constexpr uint16_t mat_apply(const Mat& L, uint16_t x) {
    uint16_t r=0; for (int b=0;b<NQ;++b) if ((x>>b)&1u) r=(uint16_t)(r ^ L.col[b]); return r;
}
constexpr Mat inverse(const Mat& L, bool& ok) {
    uint32_t lrow[NQ]={}, irow[NQ]={};
    for (int r=0;r<NQ;++r){ lrow[r]=mat_row(L,r); irow[r]=1u<<r; }
    for (int c=0;c<NQ;++c){
        int piv=-1;
        for (int r=c;r<NQ;++r) if ((lrow[r]>>c)&1u){ piv=r; break; }
        if (piv<0){ ok=false; return identity(); }
        uint32_t tl=lrow[c]; lrow[c]=lrow[piv]; lrow[piv]=tl;
        uint32_t ti=irow[c]; irow[c]=irow[piv]; irow[piv]=ti;
        for (int r=0;r<NQ;++r) if (r!=c && ((lrow[r]>>c)&1u)){ lrow[r]^=lrow[c]; irow[r]^=irow[c]; }
    }
    Mat inv{};
    for (int w=0;w<NQ;++w){ uint16_t cv=0; for (int r=0;r<NQ;++r) cv=(uint16_t)(cv | (((irow[r]>>w)&1u)<<r)); inv.col[w]=cv; }
    return inv;
}
constexpr Mat mat_mul(const Mat& A, const Mat& B) {  // (A∘B) e_j = A(B e_j)
    Mat r{}; for (int j=0;j<NQ;++j) r.col[j]=mat_apply(A,B.col[j]); return r;
}
constexpr uint16_t mat_tapply(const Mat& M, uint16_t r) {  // M^T r
    uint16_t v=0; for (int j=0;j<NQ;++j) v=(uint16_t)(v | ((uint16_t)(cpop16(M.col[j]&r)&1)<<j)); return v;
}
constexpr Tables build() {
    Tables t{}; t.ok = true;
    Mat L = identity();
    for (int p=0;p<NPASS;++p) {
        if (p>0) { Mat Ln{}; for (int b=0;b<NQ;++b) Ln.col[b]=ring_apply(L.col[b]); L=Ln; }
        bool ok = true; Mat inv = inverse(L, ok); if (!ok) t.ok = false;
        for (int w=0;w<NQ;++w) {
            t.mask[p][w] = inv.col[w];
            t.rho [p][w] = mat_row(L,w);
            if (mat_apply(L, inv.col[w]) != (uint16_t)(1u<<w)) t.ok = false;
        }
    }
    for (int w=0;w<NQ;++w) t.zrho[w] = mat_row(L,w);
    return t;
}
constexpr Tables TBL = build();
static_assert(TBL.ok, "GF2 table build failed");
static_assert(TBL.mask[0][0]==1 && TBL.rho[0][0]==1, "pass0 w0");
static_assert(TBL.mask[0][13]==(1u<<13) && TBL.rho[0][13]==(1u<<13), "pass0 w13");
static_assert(TBL.mask[1][0]==3,      "pass1 w0 mask");
static_assert(TBL.rho [1][0]==0x3FFE, "pass1 w0 rho");
static_assert(TBL.mask[1][12]==0x3000,"pass1 w12 mask");

// ---------------- compile-time frame scheduler ----------------
// Storage index y (14b): y[1:0]=quad elem (J), y[9:2]=tid (y[7:2] lane, y[9:8] wave),
// y[13:10]=quad idx per thread (IT). stored[y] = A[T·y]. Per phase: 4 gate masks hosted
// at T cols 10..13; gate applied as register butterfly with mu = T^{-1}m supported on
// {0,1,10..13}. Global "tagged" lane cols lam_k = e_k ^ e_{u} at cols 2..4 make
// low-supported masks hostable. Remap into each phase: M = Tprev^{-1} T; constraints
// (checked): M fixes e0,e1; cols>=2 have bits{0,1}=0; cols 2..4 have exact-identity
// [4:2]-projection (octet bank rule -> conflict-free b128 reads).
#define MAXPH 28
struct Sched {
    bool ok; int nph; int ngtot;
    uint16_t M[MAXPH][NQ];
    int ng[MAXPH];
    int gw[MAXPH][6]; int gsc[MAXPH][6];
    uint16_t gmu[MAXPH][6];     // 6-bit local mask: (muIT<<2)|muJ
    uint16_t grho[MAXPH][6];    // rho' in y-space
    uint16_t zrho[NQ];
};
struct Basis { uint16_t lead[16]; };
constexpr bool binsert(Basis& B, uint16_t v) {
    v &= 0x3FFC;  // quotient by quad dims
    while (v) {
        int t=-1; for (int i=15;i>=0;--i) if ((v>>i)&1u){ t=i; break; }
        if (!B.lead[t]) { B.lead[t]=v; return true; }
        v = (uint16_t)(v ^ B.lead[t]);
    }
    return false;
}
constexpr Sched try_build(int u0,int u1,int u2) {
    Sched S{}; S.ok=true; S.nph=0; S.ngtot=0;
    uint16_t lam[3] = { (uint16_t)((1u<<2)|(1u<<u0)), (uint16_t)((1u<<3)|(1u<<u1)), (uint16_t)((1u<<4)|(1u<<u2)) };
    Mat prevT = identity();
    for (int p=1;p<NPASS;++p) {
        bool done[NQ]={}; bool isq[NQ]={}; int nleft=0;
        for (int w=0;w<NQ;++w){ if ((TBL.mask[p][w] & ~3u)==0) isq[w]=true; else ++nleft; }
        bool first=true; int guard=0;
        while (nleft>0) {
            if (S.nph>=MAXPH || ++guard>MAXPH){ S.ok=false; return S; }
            int ph=S.nph++;
            Basis B{};
            if(!binsert(B,lam[0])||!binsert(B,lam[1])||!binsert(B,lam[2])){ S.ok=false; return S; }
            Mat T{}; T.col[0]=1; T.col[1]=2; T.col[2]=lam[0]; T.col[3]=lam[1]; T.col[4]=lam[2];
            int slotw[4]={}; int nsl=0;
            for (int round=0;round<2;++round)
                for (int w=0;w<NQ;++w) {
                    if (nsl==4) break;
                    if (done[w]||isq[w]) continue;
                    uint16_t m=TBL.mask[p][w];
                    bool stuck = ((m & 0x3FE0u)==0);    // support within bits 0..4
                    if ((round==0)!=stuck) continue;
                    if (binsert(B,(uint16_t)(m&~3u))) {
                        T.col[10+nsl]=(uint16_t)(m&~3u); slotw[nsl++]=w; done[w]=true; --nleft;
                    }
                }
            if (nsl==0){ S.ok=false; return S; }
            // parked completion: cols 5..9 then unused slots
            int freecols[9]; int nf=0;
            for (int c=5;c<=9;++c)        freecols[nf++]=c;
            for (int c=10+nsl;c<=13;++c)  freecols[nf++]=c;
            int filled=0;
            for (int b=5;b<NQ && filled<nf;++b) if (binsert(B,(uint16_t)(1u<<b))) T.col[freecols[filled++]]=(uint16_t)(1u<<b);
            for (int b=2;b<5  && filled<nf;++b) if (binsert(B,(uint16_t)(1u<<b))) T.col[freecols[filled++]]=(uint16_t)(1u<<b);
            if (filled!=nf){ S.ok=false; return S; }
            bool iok=true; Mat Ti=inverse(T,iok); if(!iok){ S.ok=false; return S; }
            S.ng[ph]=0;
            for (int i=0;i<nsl;++i) {
                int w=slotw[i]; uint16_t m=TBL.mask[p][w];
                uint16_t mu=mat_apply(Ti,m);
                if (mu & 0x03FCu){ S.ok=false; return S; }   // support must be {0,1,10..13}
                int gi=S.ng[ph]++; ++S.ngtot;
                S.gw[ph][gi]=w; S.gsc[ph][gi]=(p==NPASS-1)?0:1;
                S.gmu[ph][gi]=(uint16_t)(((mu>>10)<<2)|(mu&3u));
                S.grho[ph][gi]=mat_tapply(T,TBL.rho[p][w]);
            }
            if (first) {
                for (int w=0;w<NQ;++w) if (isq[w]) {
                    int gi=S.ng[ph]++; ++S.ngtot;
                    S.gw[ph][gi]=w; S.gsc[ph][gi]=(p==NPASS-1)?0:1;
                    S.gmu[ph][gi]=(uint16_t)(TBL.mask[p][w]&3u);
                    S.grho[ph][gi]=mat_tapply(T,TBL.rho[p][w]);
                }
                first=false;
            }
            bool iok2=true; Mat Pi=inverse(prevT,iok2); if(!iok2){ S.ok=false; return S; }
            Mat M=mat_mul(Pi,T);
            if (M.col[0]!=1u || M.col[1]!=2u){ S.ok=false; return S; }
            for (int c=2;c<NQ;++c) if (M.col[c]&3u){ S.ok=false; return S; }
            for (int c=2;c<5;++c)  if ((M.col[c]&0x1Cu)!=(1u<<c)){ S.ok=false; return S; }
            for (int c=0;c<NQ;++c) S.M[ph][c]=M.col[c];
            prevT=T;
        }
    }
    for (int w=0;w<NQ;++w) S.zrho[w]=mat_tapply(prevT,TBL.zrho[w]);
    return S;
}
constexpr Sched build_sched() {
    Sched S = try_build(5,6,7);    if (S.ok) return S;
    S = try_build(8,9,10);         if (S.ok) return S;
    S = try_build(11,12,13);       if (S.ok) return S;
    S = try_build(5,9,13);         if (S.ok) return S;
    S = try_build(13,9,5);         if (S.ok) return S;
    S = try_build(7,5,6);          return S;
}
constexpr Sched SCH = build_sched();
static_assert(SCH.ok, "frame schedule build failed");
static_assert(SCH.ngtot == 4*NQ, "not all 56 gates scheduled");
constexpr int NPH = SCH.nph;
static_assert(NPH >= 8 && NPH <= MAXPH, "unexpected phase count");

// ---------------- device code ----------------
template<int PH> __device__ __forceinline__
void run_phase(float (&q)[64], unsigned tid, float4* Aq, const float (&CS)[2][2][NQ]) {
    // ---- remap read: addr(quad) = M·y >> 2 ----
    unsigned tq = 0;
    #pragma unroll
    for (int k=0;k<8;++k) {
        const unsigned col = ((unsigned)SCH.M[PH][2+k]) >> 2;
        tq ^= (((tid>>k)&1u) ? col : 0u);
    }
    #pragma unroll
    for (int IT=0;IT<16;++IT) {
        unsigned cit = 0;
        if (IT&1) cit ^= ((unsigned)SCH.M[PH][10])>>2;
        if (IT&2) cit ^= ((unsigned)SCH.M[PH][11])>>2;
        if (IT&4) cit ^= ((unsigned)SCH.M[PH][12])>>2;
        if (IT&8) cit ^= ((unsigned)SCH.M[PH][13])>>2;
        const float4 v = Aq[tq ^ cit];
        q[IT*4+0]=v.x; q[IT*4+1]=v.y; q[IT*4+2]=v.z; q[IT*4+3]=v.w;
    }
    // ---- gates: register butterflies, signs folded at compile time ----
    #pragma unroll
    for (int gi=0; gi<SCH.ng[PH]; ++gi) {
        const int w = SCH.gw[PH][gi], sc = SCH.gsc[PH][gi];
        const unsigned mu  = SCH.gmu[PH][gi];
        const unsigned rho = SCH.grho[PH][gi];
        const float cc = CS[sc][0][w], ss = CS[sc][1][w];
        const unsigned pt = __popc(rho & (tid<<2)) & 1u;     // runtime part of parity
        const float fp = pt ? ss : -ss;                       // coef for ct=0
        const float fn = -fp;                                 // coef for ct=1
        #pragma unroll
        for (int l=0;l<64;++l) {
            const unsigned piv = 1u << (31 - __builtin_clz(mu));
            if (l & piv) continue;                            // folds after unroll
            const int l2 = l ^ (int)mu;
            const unsigned ya = (((unsigned)l >>2)<<10) | ((unsigned)l &3u);
            const unsigned yb = (((unsigned)l2>>2)<<10) | ((unsigned)l2&3u);
            const float a=q[l], b=q[l2];
            q[l]  = fmaf((__popc(rho&ya)&1) ? fn : fp, b, cc*a);
            q[l2] = fmaf((__popc(rho&yb)&1) ? fn : fp, a, cc*b);
        }
    }
}

template<int PH> __device__ __forceinline__
void phases_from(float (&q)[64], unsigned tid, float4* Aq, const float (&CS)[2][2][NQ]) {
    if constexpr (PH < NPH) {
        run_phase<PH>(q, tid, Aq, CS);
        if constexpr (PH+1 < NPH) {
            __syncthreads();                                  // all reads done before overwrite
            #pragma unroll
            for (int IT=0;IT<16;++IT)
                Aq[((unsigned)IT<<8)|tid] = make_float4(q[IT*4],q[IT*4+1],q[IT*4+2],q[IT*4+3]);
            __syncthreads();
        }
        phases_from<PH+1>(q, tid, Aq, CS);
    }
}

// One workgroup per circuit (b,g): 256 threads x 64 amps in registers; 64KB LDS
// permutation buffer; 2 WG/CU.
__global__ __launch_bounds__(NTH)
void qgen_kernel(const float* __restrict__ x, const float* __restrict__ W,
                 const float* __restrict__ bias, float* __restrict__ out)
{
    __shared__ float4 Aq[4096];
    __shared__ float CS[2][2][NQ];
    __shared__ float zacc[NQ];

    const int blk = blockIdx.x;
    const int bb  = blk >> 3;
    const int g   = blk & 7;
    const unsigned tid = threadIdx.x;

    if (tid < NQ) {
        float acc = bias[g*NQ + tid];
        #pragma unroll
        for (int qq=0;qq<NQ;++qq) acc += x[bb*NQ+qq] * W[(g*NQ+qq)*NQ + tid];
        float h = 0.5f*acc;
        CS[0][0][tid]=cosf(h);   CS[0][1][tid]=sinf(h);
        CS[1][0][tid]=cosf(acc); CS[1][1][tid]=sinf(acc);
        zacc[tid]=0.f;
    }
    __syncthreads();

    float q[64];
    // ---- product-state fill (identity frame): wires 0,1<-J; 2..9<-tid; 10..13<-IT ----
    {
        float tp = 1.f;
        #pragma unroll
        for (int k=0;k<8;++k) tp *= ((tid>>k)&1u) ? CS[0][1][2+k] : CS[0][0][2+k];
        const float c0=CS[0][0][0], s0=CS[0][1][0], c1=CS[0][0][1], s1=CS[0][1][1];
        #pragma unroll
        for (int IT=0;IT<16;++IT) {
            float f = tp;
            #pragma unroll
            for (int b=0;b<4;++b) f *= ((IT>>b)&1) ? CS[0][1][10+b] : CS[0][0][10+b];
            q[IT*4+0]=f*c0*c1; q[IT*4+1]=f*s0*c1; q[IT*4+2]=f*c0*s1; q[IT*4+3]=f*s0*s1;
        }
        #pragma unroll
        for (int IT=0;IT<16;++IT)
            Aq[((unsigned)IT<<8)|tid] = make_float4(q[IT*4],q[IT*4+1],q[IT*4+2],q[IT*4+3]);
        __syncthreads();
    }

    phases_from<0>(q, tid, Aq, CS);

    // ---- measurement in final frame (registers; compile-time sign patterns) ----
    float acc[NQ];
    #pragma unroll
    for (int w=0;w<NQ;++w) acc[w]=0.f;
    #pragma unroll
    for (int l=0;l<64;++l) {
        const float pr = q[l]*q[l];
        #pragma unroll
        for (int w=0;w<NQ;++w) {
            const unsigned zr = SCH.zrho[w];
            const unsigned ya = (((unsigned)l>>2)<<10) | ((unsigned)l&3u);
            acc[w] += (__popc(zr&ya)&1) ? -pr : pr;
        }
    }
    #pragma unroll
    for (int w=0;w<NQ;++w) {
        const unsigned zr = SCH.zrho[w];
        if (__popc(zr & (tid<<2)) & 1) acc[w] = -acc[w];
        #pragma unroll
        for (int off=32; off; off>>=1) acc[w] += __shfl_down(acc[w], off, 64);
    }
    if ((tid & 63u) == 0) {
        #pragma unroll
        for (int w=0;w<NQ;++w) atomicAdd(&zacc[w], acc[w]);
    }
    __syncthreads();
    if (tid < NQ) out[blk*NQ + tid] = zacc[tid];
}

extern "C" void kernel_launch(void* const* d_in, const int* in_sizes, int n_in,
                              void* d_out, int out_size, void* d_ws, size_t ws_size,
                              hipStream_t stream) {
    (void)in_sizes; (void)n_in; (void)d_ws; (void)ws_size; (void)out_size;
    const float* x    = (const float*)d_in[0];   // [512,14]
    const float* W    = (const float*)d_in[1];   // [8,14,14]
    const float* bias = (const float*)d_in[2];   // [8,14]
    float* out = (float*)d_out;                  // [512, 8*14]
    qgen_kernel<<<dim3(NBLK), dim3(NTH), 0, stream>>>(x, W, bias, out);
}

// Round 6
// 302.255 us; speedup vs baseline: 3.9678x; 1.0009x over previous
//
#include <hip/hip_runtime.h>
#include <stdint.h>

#define NQ 14
#define NPASS 5
#define NGEN 8
#define NTH 256
#define NBLK (512*NGEN)

typedef float f2 __attribute__((ext_vector_type(2)));

// ---------------- constexpr helpers ----------------
constexpr int cpop16(uint32_t x){ int n=0; for(int i=0;i<16;++i) n+=(x>>i)&1; return n; }

// ---------------- GF(2) circuit algebra (HW-verified rounds 4/5) ----------------
struct Mat { uint16_t col[NQ]; };
struct Tables {
    uint16_t mask[NPASS][NQ];  // pairing mask m = L^{-1} e_w
    uint16_t rho [NPASS][NQ];  // role parity row_w(L)
    uint16_t zrho[NQ];         // measurement parity rows (final L)
    bool ok;
};
constexpr uint16_t ring_apply(uint16_t j) {
    for (int i = 0; i < NQ; ++i) { int t=(i+1)%NQ; j=(uint16_t)(j ^ (((j>>i)&1u)<<t)); }
    return j;
}
constexpr Mat identity() { Mat m{}; for (int i=0;i<NQ;++i) m.col[i]=(uint16_t)(1u<<i); return m; }
constexpr uint16_t mat_row(const Mat& L, int r) {
    uint16_t v=0; for (int b=0;b<NQ;++b) v=(uint16_t)(v | (((L.col[b]>>r)&1u)<<b)); return v;
}
constexpr uint16_t mat_apply(const Mat& L, uint16_t x) {
    uint16_t r=0; for (int b=0;b<NQ;++b) if ((x>>b)&1u) r=(uint16_t)(r ^ L.col[b]); return r;
}
constexpr Mat inverse(const Mat& L, bool& ok) {
    uint32_t lrow[NQ]={}, irow[NQ]={};
    for (int r=0;r<NQ;++r){ lrow[r]=mat_row(L,r); irow[r]=1u<<r; }
    for (int c=0;c<NQ;++c){
        int piv=-1;
        for (int r=c;r<NQ;++r) if ((lrow[r]>>c)&1u){ piv=r; break; }
        if (piv<0){ ok=false; return identity(); }
        uint32_t tl=lrow[c]; lrow[c]=lrow[piv]; lrow[piv]=tl;
        uint32_t ti=irow[c]; irow[c]=irow[piv]; irow[piv]=ti;
        for (int r=0;r<NQ;++r) if (r!=c && ((lrow[r]>>c)&1u)){ lrow[r]^=lrow[c]; irow[r]^=irow[c]; }
    }
    Mat inv{};
    for (int w=0;w<NQ;++w){ uint16_t cv=0; for (int r=0;r<NQ;++r) cv=(uint16_t)(cv | (((irow[r]>>w)&1u)<<r)); inv.col[w]=cv; }
    return inv;
}
constexpr Mat mat_mul(const Mat& A, const Mat& B) {
    Mat r{}; for (int j=0;j<NQ;++j) r.col[j]=mat_apply(A,B.col[j]); return r;
}
constexpr uint16_t mat_tapply(const Mat& M, uint16_t r) {  // M^T r
    uint16_t v=0; for (int j=0;j<NQ;++j) v=(uint16_t)(v | ((uint16_t)(cpop16(M.col[j]&r)&1)<<j)); return v;
}
constexpr Tables build() {
    Tables t{}; t.ok = true;
    Mat L = identity();
    for (int p=0;p<NPASS;++p) {
        if (p>0) { Mat Ln{}; for (int b=0;b<NQ;++b) Ln.col[b]=ring_apply(L.col[b]); L=Ln; }
        bool ok = true; Mat inv = inverse(L, ok); if (!ok) t.ok = false;
        for (int w=0;w<NQ;++w) {
            t.mask[p][w] = inv.col[w];
            t.rho [p][w] = mat_row(L,w);
            if (mat_apply(L, inv.col[w]) != (uint16_t)(1u<<w)) t.ok = false;
        }
    }
    for (int w=0;w<NQ;++w) t.zrho[w] = mat_row(L,w);
    return t;
}
constexpr Tables TBL = build();
static_assert(TBL.ok, "GF2 table build failed");
static_assert(TBL.mask[0][0]==1 && TBL.rho[0][0]==1, "pass0 w0");
static_assert(TBL.mask[1][0]==3,      "pass1 w0 mask");
static_assert(TBL.rho [1][0]==0x3FFE, "pass1 w0 rho");
static_assert(TBL.mask[1][12]==0x3000,"pass1 w12 mask");

// ---------------- compile-time frame scheduler v2 (max hosting) ----------------
// Storage index y: y[1:0]=J (float4 elem), y[9:2]=tid, y[13:10]=IT (quad/thread).
// stored[y] = A[T*y]. Frame hosts every pending gate whose mu = T^{-1} m has
// support in local dims {0,1,10..13}. Cross-pass rollover allowed once the
// current pass is fully hosted (intra-pass gates commute; order preserved).
#define MAXPH 28
#define MAXG 14
struct Sched {
    bool ok; int nph; int ngtot;
    uint16_t M[MAXPH][NQ];
    int ng[MAXPH];
    int gw[MAXPH][MAXG]; int gsc[MAXPH][MAXG];
    uint16_t gmu[MAXPH][MAXG];  // 6-bit local mask: (muIT<<2)|muJ
    uint16_t grho[MAXPH][MAXG]; // rho in y-space
    uint16_t zrho[NQ];
};
struct Basis { uint16_t lead[16]; };
constexpr bool binsert(Basis& B, uint16_t v) {
    v &= 0x3FFC;
    while (v) {
        int t=-1; for (int i=15;i>=0;--i) if ((v>>i)&1u){ t=i; break; }
        if (!B.lead[t]) { B.lead[t]=v; return true; }
        v = (uint16_t)(v ^ B.lead[t]);
    }
    return false;
}
constexpr Sched try_build(int u0,int u1,int u2) {
    Sched S{}; S.ok=true; S.nph=0; S.ngtot=0;
    const uint16_t lam[3] = { (uint16_t)((1u<<2)|(1u<<u0)), (uint16_t)((1u<<3)|(1u<<u1)), (uint16_t)((1u<<4)|(1u<<u2)) };
    Mat prevT = identity();
    bool done[NPASS][NQ] = {};
    int pend[NPASS] = {};
    for (int p=1;p<NPASS;++p) pend[p]=NQ;
    int pc = 1; int guard = 0;
    while (pc < NPASS) {
        if (pend[pc]==0) { ++pc; continue; }
        if (S.nph>=MAXPH || ++guard>MAXPH){ S.ok=false; return S; }
        const int ph = S.nph++;
        Basis B{};
        if(!binsert(B,lam[0])||!binsert(B,lam[1])||!binsert(B,lam[2])){ S.ok=false; return S; }
        Mat T{}; T.col[0]=1; T.col[1]=2; T.col[2]=lam[0]; T.col[3]=lam[1]; T.col[4]=lam[2];
        int nsl=0;
        for (int round=0;round<2 && nsl<4;++round)
            for (int w=0;w<NQ && nsl<4;++w) {
                if (done[pc][w]) continue;
                const uint16_t m=TBL.mask[pc][w];
                if ((m & ~3u)==0) continue;               // quad: swept for free
                const bool stuck = ((m & 0x3FE0u)==0);    // support within bits 0..4
                if ((round==0)!=stuck) continue;
                if (binsert(B,(uint16_t)(m&~3u))) T.col[10+nsl++]=(uint16_t)(m&~3u);
            }
        // complete basis with singletons (always possible: e2..e13 span)
        int freecols[9]; int nf=0;
        for (int c=5;c<=9;++c)        freecols[nf++]=c;
        for (int c=10+nsl;c<=13;++c)  freecols[nf++]=c;
        int filled=0;
        for (int b=5;b<NQ && filled<nf;++b) if (binsert(B,(uint16_t)(1u<<b))) T.col[freecols[filled++]]=(uint16_t)(1u<<b);
        for (int b=2;b<5  && filled<nf;++b) if (binsert(B,(uint16_t)(1u<<b))) T.col[freecols[filled++]]=(uint16_t)(1u<<b);
        if (filled!=nf){ S.ok=false; return S; }
        bool iok=true; const Mat Ti=inverse(T,iok); if(!iok){ S.ok=false; return S; }
        // sweep current pass
        S.ng[ph]=0;
        for (int w=0;w<NQ;++w) {
            if (done[pc][w]) continue;
            const uint16_t mu=mat_apply(Ti,TBL.mask[pc][w]);
            if (mu & 0x03FCu) continue;
            const int gi=S.ng[ph]++; ++S.ngtot;
            S.gw[ph][gi]=w; S.gsc[ph][gi]=(pc==NPASS-1)?0:1;
            S.gmu[ph][gi]=(uint16_t)(((mu>>10)<<2)|(mu&3u));
            S.grho[ph][gi]=mat_tapply(T,TBL.rho[pc][w]);
            done[pc][w]=true; --pend[pc];
        }
        if (S.ng[ph]==0){ S.ok=false; return S; }
        // rollover into next pass if this one is complete
        if (pend[pc]==0 && pc+1<NPASS) {
            const int p2=pc+1;
            for (int w=0;w<NQ;++w) {
                if (done[p2][w]) continue;
                const uint16_t mu=mat_apply(Ti,TBL.mask[p2][w]);
                if (mu & 0x03FCu) continue;
                const int gi=S.ng[ph]++; ++S.ngtot;
                S.gw[ph][gi]=w; S.gsc[ph][gi]=(p2==NPASS-1)?0:1;
                S.gmu[ph][gi]=(uint16_t)(((mu>>10)<<2)|(mu&3u));
                S.grho[ph][gi]=mat_tapply(T,TBL.rho[p2][w]);
                done[p2][w]=true; --pend[p2];
            }
        }
        // remap matrix + structural checks (auto-satisfied; defense in depth)
        bool iok2=true; const Mat Pi=inverse(prevT,iok2); if(!iok2){ S.ok=false; return S; }
        const Mat M=mat_mul(Pi,T);
        if (M.col[0]!=1u || M.col[1]!=2u){ S.ok=false; return S; }
        for (int c=2;c<NQ;++c) if (M.col[c]&3u){ S.ok=false; return S; }
        for (int c=2;c<5;++c)  if ((M.col[c]&0x1Cu)!=(1u<<c)){ S.ok=false; return S; }
        for (int c=0;c<NQ;++c) S.M[ph][c]=M.col[c];
        prevT=T;
    }
    for (int w=0;w<NQ;++w) S.zrho[w]=mat_tapply(prevT,TBL.zrho[w]);
    return S;
}
constexpr Sched build_sched() {
    Sched S = try_build(5,6,7);    if (S.ok) return S;
    S = try_build(8,9,10);         if (S.ok) return S;
    S = try_build(11,12,13);       if (S.ok) return S;
    S = try_build(5,9,13);         if (S.ok) return S;
    S = try_build(13,9,5);         if (S.ok) return S;
    S = try_build(6,7,8);          if (S.ok) return S;
    S = try_build(9,10,11);        if (S.ok) return S;
    S = try_build(7,5,6);          return S;
}
constexpr Sched SCH = build_sched();
static_assert(SCH.ok, "frame schedule build failed");
static_assert(SCH.ngtot == 4*NQ, "not all 56 gates scheduled");
constexpr int NPH = SCH.nph;
static_assert(NPH >= 5 && NPH <= MAXPH, "unexpected phase count");

// ---------------- device code ----------------
// Register file: 32 x float2 per thread. qq[i]: i bit0 = y1, bits1..4 = IT;
// float2 elements are y0 = 0/1.  (l = y0 | y1<<1 | IT<<2.)
template<int PH> __device__ __forceinline__
void run_phase(f2 (&qq)[32], unsigned tid, float4* Aq, const float (&CS)[2][2][NQ]) {
    // ---- remap read: quad addr = (M*y) >> 2 ----
    unsigned tq = 0;
    #pragma unroll
    for (int k=0;k<8;++k) {
        const unsigned col = ((unsigned)SCH.M[PH][2+k]) >> 2;
        tq ^= (((tid>>k)&1u) ? col : 0u);
    }
    #pragma unroll
    for (int IT=0;IT<16;++IT) {
        unsigned cit = 0;
        if (IT&1) cit ^= ((unsigned)SCH.M[PH][10])>>2;
        if (IT&2) cit ^= ((unsigned)SCH.M[PH][11])>>2;
        if (IT&4) cit ^= ((unsigned)SCH.M[PH][12])>>2;
        if (IT&8) cit ^= ((unsigned)SCH.M[PH][13])>>2;
        const float4 v = Aq[tq ^ cit];
        qq[2*IT]   = f2{v.x, v.y};
        qq[2*IT+1] = f2{v.z, v.w};
    }
    // ---- gates: packed-f32 register butterflies ----
    #pragma unroll
    for (int gi=0; gi<SCH.ng[PH]; ++gi) {
        const int w = SCH.gw[PH][gi], sc = SCH.gsc[PH][gi];
        const unsigned lm  = SCH.gmu[PH][gi];
        const unsigned rho = SCH.grho[PH][gi];
        const float cc = CS[sc][0][w], sv = CS[sc][1][w];
        const unsigned pt = __popc(rho & (tid<<2)) & 1u;   // runtime parity part
        const float u  = pt ? sv : -sv;                    // coef when static sign=0
        const f2 c2 = {cc, cc};
        const f2 uu = {u, u};
        const f2 un = {u, -u};
        const unsigned di = ((lm>>1)&1u) | ((lm>>2)<<1);   // flip in i-space
        if (di == 0u) {
            // lm==1: intra-float2 butterfly (partner = element swap)
            #pragma unroll
            for (int i=0;i<32;++i) {
                const unsigned ya0 = ((unsigned)(i&1)<<1) | (((unsigned)i>>1)<<10);
                const int s0 = __popc(rho & ya0) & 1;
                const int s1 = __popc(rho & (ya0|1u)) & 1;
                const f2 a = qq[i];
                const f2 pv = __builtin_shufflevector(a, a, 1, 0);
                const f2 t = (s0==s1) ? uu : un;
                qq[i] = __builtin_elementwise_fma(s0 ? -t : t, pv, c2*a);
            }
        } else {
            const int dpiv = 1 << (31 - __builtin_clz(di));
            const int jsw = (int)(lm & 1u);
            #pragma unroll
            for (int i=0;i<32;++i) {
                if (i & dpiv) continue;                    // folds after unroll
                const int i2 = i ^ (int)di;
                const unsigned ya0 = ((unsigned)(i &1)<<1) | (((unsigned)i >>1)<<10);
                const unsigned yb0 = ((unsigned)(i2&1)<<1) | (((unsigned)i2>>1)<<10);
                const int sa0 = __popc(rho & ya0)&1,      sa1 = __popc(rho & (ya0|1u))&1;
                const int sb0 = __popc(rho & yb0)&1,      sb1 = __popc(rho & (yb0|1u))&1;
                const f2 a = qq[i], b = qq[i2];
                const f2 pa = jsw ? __builtin_shufflevector(b,b,1,0) : b;
                const f2 pb = jsw ? __builtin_shufflevector(a,a,1,0) : a;
                const f2 ta = (sa0==sa1) ? uu : un;
                const f2 tb = (sb0==sb1) ? uu : un;
                qq[i]  = __builtin_elementwise_fma(sa0 ? -ta : ta, pa, c2*a);
                qq[i2] = __builtin_elementwise_fma(sb0 ? -tb : tb, pb, c2*b);
            }
        }
    }
}

template<int PH> __device__ __forceinline__
void phases_from(f2 (&qq)[32], unsigned tid, float4* Aq, const float (&CS)[2][2][NQ]) {
    if constexpr (PH < NPH) {
        run_phase<PH>(qq, tid, Aq, CS);
        if constexpr (PH+1 < NPH) {
            __syncthreads();
            #pragma unroll
            for (int IT=0;IT<16;++IT)
                Aq[((unsigned)IT<<8)|tid] = make_float4(qq[2*IT].x,qq[2*IT].y,qq[2*IT+1].x,qq[2*IT+1].y);
            __syncthreads();
        }
        phases_from<PH+1>(qq, tid, Aq, CS);
    }
}

__global__ __launch_bounds__(NTH)
void qgen_kernel(const float* __restrict__ x, const float* __restrict__ W,
                 const float* __restrict__ bias, float* __restrict__ out)
{
    __shared__ float4 Aq[4096];
    __shared__ float CS[2][2][NQ];
    __shared__ float zacc[NQ];

    const int blk = blockIdx.x;
    const int bb  = blk >> 3;
    const int g   = blk & 7;
    const unsigned tid = threadIdx.x;

    if (tid < NQ) {
        float acc = bias[g*NQ + tid];
        #pragma unroll
        for (int qq2=0;qq2<NQ;++qq2) acc += x[bb*NQ+qq2] * W[(g*NQ+qq2)*NQ + tid];
        float h = 0.5f*acc;
        CS[0][0][tid]=cosf(h);   CS[0][1][tid]=sinf(h);
        CS[1][0][tid]=cosf(acc); CS[1][1][tid]=sinf(acc);
        zacc[tid]=0.f;
    }
    __syncthreads();

    f2 qq[32];
    // ---- product-state fill (identity frame): wires 0,1<-J; 2..9<-tid; 10..13<-IT ----
    {
        float tp = 1.f;
        #pragma unroll
        for (int k=0;k<8;++k) tp *= ((tid>>k)&1u) ? CS[0][1][2+k] : CS[0][0][2+k];
        const float c0=CS[0][0][0], s0=CS[0][1][0], c1=CS[0][0][1], s1=CS[0][1][1];
        #pragma unroll
        for (int IT=0;IT<16;++IT) {
            float f = tp;
            #pragma unroll
            for (int b=0;b<4;++b) f *= ((IT>>b)&1) ? CS[0][1][10+b] : CS[0][0][10+b];
            qq[2*IT]   = f2{f*c0*c1, f*s0*c1};
            qq[2*IT+1] = f2{f*c0*s1, f*s0*s1};
        }
        #pragma unroll
        for (int IT=0;IT<16;++IT)
            Aq[((unsigned)IT<<8)|tid] = make_float4(qq[2*IT].x,qq[2*IT].y,qq[2*IT+1].x,qq[2*IT+1].y);
        __syncthreads();
    }

    phases_from<0>(qq, tid, Aq, CS);

    // ---- measurement: 6-bit Walsh-Hadamard of squared amps; pick 14 coeffs ----
    f2 h[32];
    #pragma unroll
    for (int i=0;i<32;++i) h[i] = qq[i]*qq[i];
    #pragma unroll
    for (int b=0;b<5;++b) {
        #pragma unroll
        for (int i=0;i<32;++i) {
            if (i & (1<<b)) continue;
            const int i2 = i | (1<<b);
            const f2 xv = h[i], yv = h[i2];
            h[i] = xv + yv; h[i2] = xv - yv;
        }
    }
    #pragma unroll
    for (int w=0;w<NQ;++w) {
        const unsigned zr = SCH.zrho[w];
        const int ri = (int)(((zr>>1)&1u) | (((zr>>10)&0xFu)<<1));
        float val = (zr&1u) ? (h[ri].x - h[ri].y) : (h[ri].x + h[ri].y);
        if (__popc(zr & (tid<<2)) & 1) val = -val;
        #pragma unroll
        for (int off=32; off; off>>=1) val += __shfl_down(val, off, 64);
        if ((tid & 63u) == 0) atomicAdd(&zacc[w], val);
    }
    __syncthreads();
    if (tid < NQ) out[blk*NQ + tid] = zacc[tid];
}

extern "C" void kernel_launch(void* const* d_in, const int* in_sizes, int n_in,
                              void* d_out, int out_size, void* d_ws, size_t ws_size,
                              hipStream_t stream) {
    (void)in_sizes; (void)n_in; (void)d_ws; (void)ws_size; (void)out_size;
    const float* x    = (const float*)d_in[0];   // [512,14]
    const float* W    = (const float*)d_in[1];   // [8,14,14]
    const float* bias = (const float*)d_in[2];   // [8,14]
    float* out = (float*)d_out;                  // [512, 8*14]
    qgen_kernel<<<dim3(NBLK), dim3(NTH), 0, stream>>>(x, W, bias, out);
}

// Round 7
// 247.864 us; speedup vs baseline: 4.8384x; 1.2194x over previous
//
#include <hip/hip_runtime.h>
#include <hip/hip_fp16.h>
#include <stdint.h>

#define NQ 14
#define NPASS 5
#define NGEN 8
#define NTH 256
#define NBLK (512*NGEN)

typedef float f2 __attribute__((ext_vector_type(2)));

// ---------------- constexpr helpers ----------------
constexpr int cpop16(uint32_t x){ int n=0; for(int i=0;i<16;++i) n+=(x>>i)&1; return n; }

// ---------------- GF(2) circuit algebra (HW-verified rounds 4/5/6) ----------------
struct Mat { uint16_t col[NQ]; };
struct Tables {
    uint16_t mask[NPASS][NQ];  // pairing mask m = L^{-1} e_w
    uint16_t rho [NPASS][NQ];  // role parity row_w(L)
    uint16_t zrho[NQ];         // measurement parity rows (final L)
    bool ok;
};
constexpr uint16_t ring_apply(uint16_t j) {
    for (int i = 0; i < NQ; ++i) { int t=(i+1)%NQ; j=(uint16_t)(j ^ (((j>>i)&1u)<<t)); }
    return j;
}
constexpr Mat identity() { Mat m{}; for (int i=0;i<NQ;++i) m.col[i]=(uint16_t)(1u<<i); return m; }
constexpr uint16_t mat_row(const Mat& L, int r) {
    uint16_t v=0; for (int b=0;b<NQ;++b) v=(uint16_t)(v | (((L.col[b]>>r)&1u)<<b)); return v;
}
constexpr uint16_t mat_apply(const Mat& L, uint16_t x) {
    uint16_t r=0; for (int b=0;b<NQ;++b) if ((x>>b)&1u) r=(uint16_t)(r ^ L.col[b]); return r;
}
constexpr Mat inverse(const Mat& L, bool& ok) {
    uint32_t lrow[NQ]={}, irow[NQ]={};
    for (int r=0;r<NQ;++r){ lrow[r]=mat_row(L,r); irow[r]=1u<<r; }
    for (int c=0;c<NQ;++c){
        int piv=-1;
        for (int r=c;r<NQ;++r) if ((lrow[r]>>c)&1u){ piv=r; break; }
        if (piv<0){ ok=false; return identity(); }
        uint32_t tl=lrow[c]; lrow[c]=lrow[piv]; lrow[piv]=tl;
        uint32_t ti=irow[c]; irow[c]=irow[piv]; irow[piv]=ti;
        for (int r=0;r<NQ;++r) if (r!=c && ((lrow[r]>>c)&1u)){ lrow[r]^=lrow[c]; irow[r]^=irow[c]; }
    }
    Mat inv{};
    for (int w=0;w<NQ;++w){ uint16_t cv=0; for (int r=0;r<NQ;++r) cv=(uint16_t)(cv | (((irow[r]>>w)&1u)<<r)); inv.col[w]=cv; }
    return inv;
}
constexpr Mat mat_mul(const Mat& A, const Mat& B) {
    Mat r{}; for (int j=0;j<NQ;++j) r.col[j]=mat_apply(A,B.col[j]); return r;
}
constexpr uint16_t mat_tapply(const Mat& M, uint16_t r) {  // M^T r
    uint16_t v=0; for (int j=0;j<NQ;++j) v=(uint16_t)(v | ((uint16_t)(cpop16(M.col[j]&r)&1)<<j)); return v;
}
constexpr Tables build() {
    Tables t{}; t.ok = true;
    Mat L = identity();
    for (int p=0;p<NPASS;++p) {
        if (p>0) { Mat Ln{}; for (int b=0;b<NQ;++b) Ln.col[b]=ring_apply(L.col[b]); L=Ln; }
        bool ok = true; Mat inv = inverse(L, ok); if (!ok) t.ok = false;
        for (int w=0;w<NQ;++w) {
            t.mask[p][w] = inv.col[w];
            t.rho [p][w] = mat_row(L,w);
            if (mat_apply(L, inv.col[w]) != (uint16_t)(1u<<w)) t.ok = false;
        }
    }
    for (int w=0;w<NQ;++w) t.zrho[w] = mat_row(L,w);
    return t;
}
constexpr Tables TBL = build();
static_assert(TBL.ok, "GF2 table build failed");
static_assert(TBL.mask[0][0]==1 && TBL.rho[0][0]==1, "pass0 w0");
static_assert(TBL.mask[1][0]==3,      "pass1 w0 mask");
static_assert(TBL.rho [1][0]==0x3FFE, "pass1 w0 rho");
static_assert(TBL.mask[1][12]==0x3000,"pass1 w12 mask");

// ---------------- compile-time frame scheduler v2 (max hosting) ----------------
// Storage index y: y[1:0]=J (quad elem), y[9:2]=tid, y[13:10]=IT (quad/thread).
// stored[y] = A[T*y]. Frame hosts every pending gate whose mu = T^{-1} m has
// support in local dims {0,1,10..13}. Cross-pass rollover allowed once the
// current pass is fully hosted (intra-pass gates commute; order preserved).
#define MAXPH 28
#define MAXG 14
struct Sched {
    bool ok; int nph; int ngtot;
    uint16_t M[MAXPH][NQ];
    int ng[MAXPH];
    int gw[MAXPH][MAXG]; int gsc[MAXPH][MAXG];
    uint16_t gmu[MAXPH][MAXG];  // 6-bit local mask: (muIT<<2)|muJ
    uint16_t grho[MAXPH][MAXG]; // rho in y-space
    uint16_t zrho[NQ];
};
struct Basis { uint16_t lead[16]; };
constexpr bool binsert(Basis& B, uint16_t v) {
    v &= 0x3FFC;
    while (v) {
        int t=-1; for (int i=15;i>=0;--i) if ((v>>i)&1u){ t=i; break; }
        if (!B.lead[t]) { B.lead[t]=v; return true; }
        v = (uint16_t)(v ^ B.lead[t]);
    }
    return false;
}
constexpr Sched try_build(int u0,int u1,int u2) {
    Sched S{}; S.ok=true; S.nph=0; S.ngtot=0;
    const uint16_t lam[3] = { (uint16_t)((1u<<2)|(1u<<u0)), (uint16_t)((1u<<3)|(1u<<u1)), (uint16_t)((1u<<4)|(1u<<u2)) };
    Mat prevT = identity();
    bool done[NPASS][NQ] = {};
    int pend[NPASS] = {};
    for (int p=1;p<NPASS;++p) pend[p]=NQ;
    int pc = 1; int guard = 0;
    while (pc < NPASS) {
        if (pend[pc]==0) { ++pc; continue; }
        if (S.nph>=MAXPH || ++guard>MAXPH){ S.ok=false; return S; }
        const int ph = S.nph++;
        Basis B{};
        if(!binsert(B,lam[0])||!binsert(B,lam[1])||!binsert(B,lam[2])){ S.ok=false; return S; }
        Mat T{}; T.col[0]=1; T.col[1]=2; T.col[2]=lam[0]; T.col[3]=lam[1]; T.col[4]=lam[2];
        int nsl=0;
        for (int round=0;round<2 && nsl<4;++round)
            for (int w=0;w<NQ && nsl<4;++w) {
                if (done[pc][w]) continue;
                const uint16_t m=TBL.mask[pc][w];
                if ((m & ~3u)==0) continue;               // quad: swept for free
                const bool stuck = ((m & 0x3FE0u)==0);    // support within bits 0..4
                if ((round==0)!=stuck) continue;
                if (binsert(B,(uint16_t)(m&~3u))) T.col[10+nsl++]=(uint16_t)(m&~3u);
            }
        // complete basis with singletons (always possible: e2..e13 span)
        int freecols[9]; int nf=0;
        for (int c=5;c<=9;++c)        freecols[nf++]=c;
        for (int c=10+nsl;c<=13;++c)  freecols[nf++]=c;
        int filled=0;
        for (int b=5;b<NQ && filled<nf;++b) if (binsert(B,(uint16_t)(1u<<b))) T.col[freecols[filled++]]=(uint16_t)(1u<<b);
        for (int b=2;b<5  && filled<nf;++b) if (binsert(B,(uint16_t)(1u<<b))) T.col[freecols[filled++]]=(uint16_t)(1u<<b);
        if (filled!=nf){ S.ok=false; return S; }
        bool iok=true; const Mat Ti=inverse(T,iok); if(!iok){ S.ok=false; return S; }
        // sweep current pass
        S.ng[ph]=0;
        for (int w=0;w<NQ;++w) {
            if (done[pc][w]) continue;
            const uint16_t mu=mat_apply(Ti,TBL.mask[pc][w]);
            if (mu & 0x03FCu) continue;
            const int gi=S.ng[ph]++; ++S.ngtot;
            S.gw[ph][gi]=w; S.gsc[ph][gi]=(pc==NPASS-1)?0:1;
            S.gmu[ph][gi]=(uint16_t)(((mu>>10)<<2)|(mu&3u));
            S.grho[ph][gi]=mat_tapply(T,TBL.rho[pc][w]);
            done[pc][w]=true; --pend[pc];
        }
        if (S.ng[ph]==0){ S.ok=false; return S; }
        // rollover into next pass if this one is complete
        if (pend[pc]==0 && pc+1<NPASS) {
            const int p2=pc+1;
            for (int w=0;w<NQ;++w) {
                if (done[p2][w]) continue;
                const uint16_t mu=mat_apply(Ti,TBL.mask[p2][w]);
                if (mu & 0x03FCu) continue;
                const int gi=S.ng[ph]++; ++S.ngtot;
                S.gw[ph][gi]=w; S.gsc[ph][gi]=(p2==NPASS-1)?0:1;
                S.gmu[ph][gi]=(uint16_t)(((mu>>10)<<2)|(mu&3u));
                S.grho[ph][gi]=mat_tapply(T,TBL.rho[p2][w]);
                done[p2][w]=true; --pend[p2];
            }
        }
        // remap matrix + structural checks (auto-satisfied; defense in depth)
        bool iok2=true; const Mat Pi=inverse(prevT,iok2); if(!iok2){ S.ok=false; return S; }
        const Mat M=mat_mul(Pi,T);
        if (M.col[0]!=1u || M.col[1]!=2u){ S.ok=false; return S; }
        for (int c=2;c<NQ;++c) if (M.col[c]&3u){ S.ok=false; return S; }
        for (int c=2;c<5;++c)  if ((M.col[c]&0x1Cu)!=(1u<<c)){ S.ok=false; return S; }
        for (int c=0;c<NQ;++c) S.M[ph][c]=M.col[c];
        prevT=T;
    }
    for (int w=0;w<NQ;++w) S.zrho[w]=mat_tapply(prevT,TBL.zrho[w]);
    return S;
}
constexpr Sched build_sched() {
    Sched S = try_build(5,6,7);    if (S.ok) return S;
    S = try_build(8,9,10);         if (S.ok) return S;
    S = try_build(11,12,13);       if (S.ok) return S;
    S = try_build(5,9,13);         if (S.ok) return S;
    S = try_build(13,9,5);         if (S.ok) return S;
    S = try_build(6,7,8);          if (S.ok) return S;
    S = try_build(9,10,11);        if (S.ok) return S;
    S = try_build(7,5,6);          return S;
}
constexpr Sched SCH = build_sched();
static_assert(SCH.ok, "frame schedule build failed");
static_assert(SCH.ngtot == 4*NQ, "not all 56 gates scheduled");
constexpr int NPH = SCH.nph;
static_assert(NPH >= 5 && NPH <= MAXPH, "unexpected phase count");

// ---------------- fp16 LDS pack/unpack (registers stay f32) ----------------
struct __align__(8) H4 { __half2 lo, hi; };
static __device__ __forceinline__ H4 pk4(f2 a, f2 b) {
    H4 r; r.lo = __floats2half2_rn(a.x, a.y); r.hi = __floats2half2_rn(b.x, b.y); return r;
}
static __device__ __forceinline__ f2 unpk_lo(const H4& h) {
    float2 f = __half22float2(h.lo); return f2{f.x, f.y};
}
static __device__ __forceinline__ f2 unpk_hi(const H4& h) {
    float2 f = __half22float2(h.hi); return f2{f.x, f.y};
}

// ---------------- device code ----------------
// Register file: 32 x float2 per thread. qq[i]: i bit0 = y1, bits1..4 = IT;
// float2 elements are y0 = 0/1.  (l = y0 | y1<<1 | IT<<2.)
template<int PH> __device__ __forceinline__
void run_phase(f2 (&qq)[32], unsigned tid, H4* Aq, const float (&CS)[2][2][NQ]) {
    // ---- remap read: quad addr = (M*y) >> 2 ----
    unsigned tq = 0;
    #pragma unroll
    for (int k=0;k<8;++k) {
        const unsigned col = ((unsigned)SCH.M[PH][2+k]) >> 2;
        tq ^= (((tid>>k)&1u) ? col : 0u);
    }
    #pragma unroll
    for (int IT=0;IT<16;++IT) {
        unsigned cit = 0;
        if (IT&1) cit ^= ((unsigned)SCH.M[PH][10])>>2;
        if (IT&2) cit ^= ((unsigned)SCH.M[PH][11])>>2;
        if (IT&4) cit ^= ((unsigned)SCH.M[PH][12])>>2;
        if (IT&8) cit ^= ((unsigned)SCH.M[PH][13])>>2;
        const H4 v = Aq[tq ^ cit];
        qq[2*IT]   = unpk_lo(v);
        qq[2*IT+1] = unpk_hi(v);
    }
    // ---- gates: packed-f32 register butterflies ----
    #pragma unroll
    for (int gi=0; gi<SCH.ng[PH]; ++gi) {
        const int w = SCH.gw[PH][gi], sc = SCH.gsc[PH][gi];
        const unsigned lm  = SCH.gmu[PH][gi];
        const unsigned rho = SCH.grho[PH][gi];
        const float cc = CS[sc][0][w], sv = CS[sc][1][w];
        const unsigned pt = __popc(rho & (tid<<2)) & 1u;   // runtime parity part
        const float u  = pt ? sv : -sv;                    // coef when static sign=0
        const f2 c2 = {cc, cc};
        const f2 uu = {u, u};
        const f2 un = {u, -u};
        const unsigned di = ((lm>>1)&1u) | ((lm>>2)<<1);   // flip in i-space
        if (di == 0u) {
            // lm==1: intra-float2 butterfly (partner = element swap)
            #pragma unroll
            for (int i=0;i<32;++i) {
                const unsigned ya0 = ((unsigned)(i&1)<<1) | (((unsigned)i>>1)<<10);
                const int s0 = __popc(rho & ya0) & 1;
                const int s1 = __popc(rho & (ya0|1u)) & 1;
                const f2 a = qq[i];
                const f2 pv = __builtin_shufflevector(a, a, 1, 0);
                const f2 t = (s0==s1) ? uu : un;
                qq[i] = __builtin_elementwise_fma(s0 ? -t : t, pv, c2*a);
            }
        } else {
            const int dpiv = 1 << (31 - __builtin_clz(di));
            const int jsw = (int)(lm & 1u);
            #pragma unroll
            for (int i=0;i<32;++i) {
                if (i & dpiv) continue;                    // folds after unroll
                const int i2 = i ^ (int)di;
                const unsigned ya0 = ((unsigned)(i &1)<<1) | (((unsigned)i >>1)<<10);
                const unsigned yb0 = ((unsigned)(i2&1)<<1) | (((unsigned)i2>>1)<<10);
                const int sa0 = __popc(rho & ya0)&1,      sa1 = __popc(rho & (ya0|1u))&1;
                const int sb0 = __popc(rho & yb0)&1,      sb1 = __popc(rho & (yb0|1u))&1;
                const f2 a = qq[i], b = qq[i2];
                const f2 pa = jsw ? __builtin_shufflevector(b,b,1,0) : b;
                const f2 pb = jsw ? __builtin_shufflevector(a,a,1,0) : a;
                const f2 ta = (sa0==sa1) ? uu : un;
                const f2 tb = (sb0==sb1) ? uu : un;
                qq[i]  = __builtin_elementwise_fma(sa0 ? -ta : ta, pa, c2*a);
                qq[i2] = __builtin_elementwise_fma(sb0 ? -tb : tb, pb, c2*b);
            }
        }
    }
}

template<int PH> __device__ __forceinline__
void phases_from(f2 (&qq)[32], unsigned tid, H4* Aq, const float (&CS)[2][2][NQ]) {
    if constexpr (PH < NPH) {
        run_phase<PH>(qq, tid, Aq, CS);
        if constexpr (PH+1 < NPH) {
            __syncthreads();
            #pragma unroll
            for (int IT=0;IT<16;++IT)
                Aq[((unsigned)IT<<8)|tid] = pk4(qq[2*IT], qq[2*IT+1]);
            __syncthreads();
        }
        phases_from<PH+1>(qq, tid, Aq, CS);
    }
}

// 4 WG/CU (32.5KB LDS each), 16 waves/CU.
__global__ __launch_bounds__(NTH, 4)
void qgen_kernel(const float* __restrict__ x, const float* __restrict__ W,
                 const float* __restrict__ bias, float* __restrict__ out)
{
    __shared__ H4 Aq[4096];
    __shared__ float CS[2][2][NQ];
    __shared__ float zacc[NQ];

    const int blk = blockIdx.x;
    const int bb  = blk >> 3;
    const int g   = blk & 7;
    const unsigned tid = threadIdx.x;

    if (tid < NQ) {
        float acc = bias[g*NQ + tid];
        #pragma unroll
        for (int qq2=0;qq2<NQ;++qq2) acc += x[bb*NQ+qq2] * W[(g*NQ+qq2)*NQ + tid];
        float h = 0.5f*acc;
        CS[0][0][tid]=cosf(h);   CS[0][1][tid]=sinf(h);
        CS[1][0][tid]=cosf(acc); CS[1][1][tid]=sinf(acc);
        zacc[tid]=0.f;
    }
    __syncthreads();

    f2 qq[32];
    // ---- product-state fill (identity frame): wires 0,1<-J; 2..9<-tid; 10..13<-IT ----
    {
        float tp = 1.f;
        #pragma unroll
        for (int k=0;k<8;++k) tp *= ((tid>>k)&1u) ? CS[0][1][2+k] : CS[0][0][2+k];
        const float c0=CS[0][0][0], s0=CS[0][1][0], c1=CS[0][0][1], s1=CS[0][1][1];
        #pragma unroll
        for (int IT=0;IT<16;++IT) {
            float f = tp;
            #pragma unroll
            for (int b=0;b<4;++b) f *= ((IT>>b)&1) ? CS[0][1][10+b] : CS[0][0][10+b];
            qq[2*IT]   = f2{f*c0*c1, f*s0*c1};
            qq[2*IT+1] = f2{f*c0*s1, f*s0*s1};
        }
        #pragma unroll
        for (int IT=0;IT<16;++IT)
            Aq[((unsigned)IT<<8)|tid] = pk4(qq[2*IT], qq[2*IT+1]);
        __syncthreads();
    }

    phases_from<0>(qq, tid, Aq, CS);

    // ---- measurement: 6-bit Walsh-Hadamard of squared amps; pick 14 coeffs ----
    f2 h[32];
    #pragma unroll
    for (int i=0;i<32;++i) h[i] = qq[i]*qq[i];
    #pragma unroll
    for (int b=0;b<5;++b) {
        #pragma unroll
        for (int i=0;i<32;++i) {
            if (i & (1<<b)) continue;
            const int i2 = i | (1<<b);
            const f2 xv = h[i], yv = h[i2];
            h[i] = xv + yv; h[i2] = xv - yv;
        }
    }
    #pragma unroll
    for (int w=0;w<NQ;++w) {
        const unsigned zr = SCH.zrho[w];
        const int ri = (int)(((zr>>1)&1u) | (((zr>>10)&0xFu)<<1));
        float val = (zr&1u) ? (h[ri].x - h[ri].y) : (h[ri].x + h[ri].y);
        if (__popc(zr & (tid<<2)) & 1) val = -val;
        #pragma unroll
        for (int off=32; off; off>>=1) val += __shfl_down(val, off, 64);
        if ((tid & 63u) == 0) atomicAdd(&zacc[w], val);
    }
    __syncthreads();
    if (tid < NQ) out[blk*NQ + tid] = zacc[tid];
}

extern "C" void kernel_launch(void* const* d_in, const int* in_sizes, int n_in,
                              void* d_out, int out_size, void* d_ws, size_t ws_size,
                              hipStream_t stream) {
    (void)in_sizes; (void)n_in; (void)d_ws; (void)ws_size; (void)out_size;
    const float* x    = (const float*)d_in[0];   // [512,14]
    const float* W    = (const float*)d_in[1];   // [8,14,14]
    const float* bias = (const float*)d_in[2];   // [8,14]
    float* out = (float*)d_out;                  // [512, 8*14]
    qgen_kernel<<<dim3(NBLK), dim3(NTH), 0, stream>>>(x, W, bias, out);
}